// Round 9
// baseline (25.441 us; speedup 1.0000x reference)
//
#include <hip/hip_runtime.h>

// Binary-tree circuit — rank-1 factorization, 2 kernels, ZERO in-kernel
// cross-block synchronization (R7: RMW grid barriers ~35us; R8: deep flag
// DAG ~45us wait under poisoned flags.  Kernel boundary is the only barrier).
//
// Math (C=1): every node is h_l[f,b,:] = beta[b] * v_l[f,:].
//   v_{l+1}[o] = w_l[o] @ (v_l[idx_l[2o]] * v_l[idx_l[2o+1]])   (weights only)
//   beta[b]    = prod_{d<256} x[b,d];   out[b,k] = beta[b] * v8[k]
// Exact fp32 reassociation; reference underflows to exact 0 (absmax=0.0,
// R5-R8).
//
// Node A (256 blocks):
//   bid 0-15:   fused levels 0-3 for subtree g=bid -> v4g[g][64].
//               Parallel 4-round index chase (idx* prefetched first),
//               level-parallel matvecs into FRESH LDS arrays (no aliasing).
//               Each block reads its own disjoint 240KB of w0..w3.
//   bid 16-143: beta for 16 rows each -> betag[2048]  (R6-proven code).
//   bid 144+:   sink-prefetch w4..w7 slices to warm every XCD's L2 for B.
// Node B (256 blocks): plain loads (boundary-published) of v4g + betag;
//   redundant fold of levels 4-7 from warm L2 (R6-K4 proven body);
//   out rows 8*bid..8*bid+7 = beta * v8.

#define NTH 256

struct Params {
  const float* x;     const int* scope;  const float* w_in;
  const int* idx0; const float* w0;  const int* idx1; const float* w1;
  const int* idx2; const float* w2;  const int* idx3; const float* w3;
  const int* idx4; const float* w4;  const int* idx5; const float* w5;
  const int* idx6; const float* w6;  const int* idx7; const float* w7;
  float* v4g;    // ws: [16][64]
  float* betag;  // ws: [2048]
  float* out;  int B;
};

__device__ inline void sinkf4(float4 v) {
  asm volatile("" :: "v"(v.x), "v"(v.y), "v"(v.z), "v"(v.w));
}
__device__ inline void sinki4(int4 v) {
  asm volatile("" :: "v"(v.x), "v"(v.y), "v"(v.z), "v"(v.w));
}
__device__ inline float dotp(float4 w, float4 a, float4 b, float acc) {
  acc = fmaf(a.x * b.x, w.x, acc);
  acc = fmaf(a.y * b.y, w.y, acc);
  acc = fmaf(a.z * b.z, w.z, acc);
  acc = fmaf(a.w * b.w, w.w, acc);
  return acc;
}

// ---------------- Node A ----------------------------------------------------
__global__ __launch_bounds__(NTH) void ka_kernel(Params P) {
  const int t = threadIdx.x, bid = blockIdx.x;

  if (bid < 16) {
    const int g = bid;
    __shared__ int   T[32];        // [0..15]=A0, [16..23]=A1, [24..27]=A2, [28..29]=A3
    __shared__ float V0[16][64];   // leaves
    __shared__ float L0[8][64];
    __shared__ float L1[4][64];
    __shared__ float L2[2][64];

    // prefetch all idx arrays (so the chase rounds hit cache)
    if (t < 64)       sinki4(((const int4*)P.idx0)[t]);
    else if (t < 96)  sinki4(((const int4*)P.idx1)[t - 64]);
    else if (t < 112) sinki4(((const int4*)P.idx2)[t - 96]);
    else if (t < 120) sinki4(((const int4*)P.idx3)[t - 112]);

    // parallel 4-round chase
    if (t < 2)  T[28 + t] = P.idx3[2 * g + t];
    __syncthreads();
    if (t < 4)  T[24 + t] = P.idx2[2 * T[28 + (t >> 1)] + (t & 1)];
    __syncthreads();
    if (t < 8)  T[16 + t] = P.idx1[2 * T[24 + (t >> 1)] + (t & 1)];
    __syncthreads();
    if (t < 16) T[t]      = P.idx0[2 * T[16 + (t >> 1)] + (t & 1)];
    __syncthreads();

    // leaves: V0[s] = w_in[A0[s]]
    {
      const int s = t >> 4, k4 = (t & 15) * 4;
      *(float4*)&V0[s][k4] = *(const float4*)(P.w_in + (size_t)T[s] * 64 + k4);
    }
    __syncthreads();

    // lv0: 8 ops x 32 thr; thread handles outputs tt and tt+32 (full k)
    {
      const int op = t >> 5, tt = t & 31;
      const float* w = P.w0 + (size_t)T[16 + op] * 4096;
      const float* a = V0[2 * op];
      const float* b = V0[2 * op + 1];
      float acc0 = 0.f, acc1 = 0.f;
      #pragma unroll
      for (int q = 0; q < 16; ++q) {
        float4 av = *(const float4*)(a + 4 * q);
        float4 bv = *(const float4*)(b + 4 * q);
        float4 w0v = *(const float4*)(w + (size_t)tt * 64 + 4 * q);
        float4 w1v = *(const float4*)(w + (size_t)(tt + 32) * 64 + 4 * q);
        acc0 = dotp(w0v, av, bv, acc0);
        acc1 = dotp(w1v, av, bv, acc1);
      }
      L0[op][tt] = acc0;
      L0[op][tt + 32] = acc1;
    }
    __syncthreads();

    // lv1: 4 ops x 64 thr; one output per thread (full k)
    {
      const int op = t >> 6, oo = t & 63;
      const float* w = P.w1 + (size_t)T[24 + op] * 4096 + (size_t)oo * 64;
      const float* a = L0[2 * op];
      const float* b = L0[2 * op + 1];
      float acc = 0.f;
      #pragma unroll
      for (int q = 0; q < 16; ++q)
        acc = dotp(*(const float4*)(w + 4 * q), *(const float4*)(a + 4 * q),
                   *(const float4*)(b + 4 * q), acc);
      L1[op][oo] = acc;
    }
    __syncthreads();

    // lv2: 2 ops x 128 thr; 2 thr/output (half k each), shfl reduce
    {
      const int op = t >> 7, tt = t & 127, oo = tt >> 1, q0 = (tt & 1) * 32;
      const float* w = P.w2 + (size_t)T[28 + op] * 4096 + (size_t)oo * 64 + q0;
      const float* a = &L1[2 * op][q0];
      const float* b = &L1[2 * op + 1][q0];
      float acc = 0.f;
      #pragma unroll
      for (int q = 0; q < 8; ++q)
        acc = dotp(*(const float4*)(w + 4 * q), *(const float4*)(a + 4 * q),
                   *(const float4*)(b + 4 * q), acc);
      acc += __shfl_xor(acc, 1);
      if ((tt & 1) == 0) L2[op][oo] = acc;
    }
    __syncthreads();

    // lv3: 1 op x 256 thr; 4 thr/output (16 k each), shfl reduce -> v4g
    {
      const int oo = t >> 2, q0 = (t & 3) * 16;
      const float* w = P.w3 + (size_t)g * 4096 + (size_t)oo * 64 + q0;
      const float* a = &L2[0][q0];
      const float* b = &L2[1][q0];
      float acc = 0.f;
      #pragma unroll
      for (int q = 0; q < 4; ++q)
        acc = dotp(*(const float4*)(w + 4 * q), *(const float4*)(a + 4 * q),
                   *(const float4*)(b + 4 * q), acc);
      acc += __shfl_xor(acc, 1);
      acc += __shfl_xor(acc, 2);
      if ((t & 3) == 0) P.v4g[g * 64 + oo] = acc;
    }
  } else if (bid < 144) {
    // beta rows: 16 per block (R6-proven)
    const int r = (bid - 16) * 16 + (t >> 4);
    const int seg = t & 15;
    const float4* xp = (const float4*)(P.x + (size_t)r * 256 + seg * 16);
    float4 u0 = xp[0], u1 = xp[1], u2 = xp[2], u3 = xp[3];
    float pr = ((u0.x * u0.y) * (u0.z * u0.w)) * ((u1.x * u1.y) * (u1.z * u1.w))
             * ((u2.x * u2.y) * (u2.z * u2.w)) * ((u3.x * u3.y) * (u3.z * u3.w));
    pr *= __shfl_xor(pr, 1);
    pr *= __shfl_xor(pr, 2);
    pr *= __shfl_xor(pr, 4);
    pr *= __shfl_xor(pr, 8);
    if (seg == 0) P.betag[r] = pr;
  } else {
    // L2 warm for node B: prefetch slices of concat(w4,w5,w6,w7) = 61440 floats
    auto pref_slice = [&](int s) {
      const int base = s * 3840;
      #pragma unroll
      for (int i = t * 4; i < 3840; i += NTH * 4) {
        const int fi = base + i;
        const float* p;
        if (fi < 32768)       p = P.w4 + fi;
        else if (fi < 49152)  p = P.w5 + (fi - 32768);
        else if (fi < 57344)  p = P.w6 + (fi - 49152);
        else                  p = P.w7 + (fi - 57344);
        sinkf4(*(const float4*)p);
      }
    };
    const int s = (bid - 144) >> 3;        // 0..13 per XCD
    pref_slice(s);
    if (s < 2) pref_slice(s + 14);         // cover the remaining 2 slices
  }
}

// ---------------- Node B: redundant fold levels 4-7 + output ----------------
__global__ __launch_bounds__(NTH) void kb_kernel(Params P) {
  const int t = threadIdx.x, bid = blockIdx.x;
  __shared__ float VA[16][64];
  __shared__ float VB[8][64];
  __shared__ float v8[64];
  __shared__ float beta_s[8];

  if (t < 8) beta_s[t] = P.betag[bid * 8 + t];
  #pragma unroll
  for (int rr = 0; rr < 4; ++rr) {
    const int idx = rr * 256 + t;
    VA[rr * 4 + (t >> 6)][idx & 63] = P.v4g[idx];
  }
  __syncthreads();

  const float* wl[4] = {P.w4, P.w5, P.w6, P.w7};
  const int*   il[4] = {P.idx4, P.idx5, P.idx6, P.idx7};
  const int G = t >> 6, lane = t & 63;
  #pragma unroll
  for (int lev = 0; lev < 4; ++lev) {
    const int nops = 8 >> lev;
    for (int op = G; op < nops; op += 4) {
      const int i0 = il[lev][2 * op], i1 = il[lev][2 * op + 1];
      const float* a = (lev & 1) ? VB[i0] : VA[i0];
      const float* b = (lev & 1) ? VB[i1] : VA[i1];
      const float* wp = wl[lev] + (size_t)op * 4096 + lane * 64;
      float acc = 0.f;
      #pragma unroll
      for (int qq = 0; qq < 16; ++qq)
        acc = dotp(*(const float4*)(wp + 4 * qq), *(const float4*)(a + 4 * qq),
                   *(const float4*)(b + 4 * qq), acc);
      float* dst = (lev == 3) ? v8 : ((lev & 1) ? VA[op] : VB[op]);
      dst[lane] = acc;
    }
    __syncthreads();
  }

  {
    const int row = t >> 5, c0 = (t & 31) * 2;
    const float be = beta_s[row];
    float2 v = *(const float2*)&v8[c0];
    *(float2*)(P.out + (size_t)(bid * 8 + row) * 64 + c0) =
        make_float2(be * v.x, be * v.y);
  }
}

extern "C" void kernel_launch(void* const* d_in, const int* in_sizes, int n_in,
                              void* d_out, int out_size, void* d_ws, size_t ws_size,
                              hipStream_t stream) {
  Params P;
  P.x     = (const float*)d_in[0];
  P.scope = (const int*)d_in[1];
  P.w_in  = (const float*)d_in[2];
  P.idx0 = (const int*)d_in[3];  P.w0 = (const float*)d_in[4];
  P.idx1 = (const int*)d_in[5];  P.w1 = (const float*)d_in[6];
  P.idx2 = (const int*)d_in[7];  P.w2 = (const float*)d_in[8];
  P.idx3 = (const int*)d_in[9];  P.w3 = (const float*)d_in[10];
  P.idx4 = (const int*)d_in[11]; P.w4 = (const float*)d_in[12];
  P.idx5 = (const int*)d_in[13]; P.w5 = (const float*)d_in[14];
  P.idx6 = (const int*)d_in[15]; P.w6 = (const float*)d_in[16];
  P.idx7 = (const int*)d_in[17]; P.w7 = (const float*)d_in[18];
  P.B    = in_sizes[0] / 256;              // 2048
  float* ws = (float*)d_ws;
  P.v4g   = ws;                            // [16][64]
  P.betag = ws + 16 * 64;                  // [2048]
  P.out   = (float*)d_out;

  ka_kernel<<<256, NTH, 0, stream>>>(P);
  kb_kernel<<<256, NTH, 0, stream>>>(P);
}

// Round 10
// 23.760 us; speedup vs baseline: 1.0708x; 1.0708x over previous
//
#include <hip/hip_runtime.h>

// Binary-tree circuit — rank-1 factorization, 3 kernels, zero in-kernel
// cross-block sync, and NO block ever streams more than ~48KB of cold HBM
// (per-CU cold-HBM streaming is ~24 GB/s -> 240KB/block = 10us, the hidden
// cost in R6/R9).
//
// Math (C=1): every node is h_l[f,b,:] = beta[b] * v_l[f,:].
//   v_{l+1}[o] = w_l[o] @ (v_l[idx_l[2o]] * v_l[idx_l[2o+1]])   (weights only)
//   beta[b]    = prod_{d<256} x[b,d];   out[b,k] = beta[b] * v8[k]
// Exact fp32 reassociation; reference underflows to exact 0 (absmax=0.0,
// R5-R9).
//
// Node A (256 blocks):
//   bid 0-63:   fused level-0 pair + level-1 -> h2g[bid][64]   (R8-proven)
//   bid 64-191: beta, 16 rows each -> betag[2048]              (R6-proven)
//   bid 192+:   sink-prefetch 16KB slice of w2..w7 (1MB total) -> L3/L2 warm
// Node B (16 blocks): levels 2-3 for subtree g -> v4g[g][64]   (R8-proven,
//   plain loads of h2g; kernel boundary publishes).
// Node C (256 blocks): redundant fold levels 4-7 from warm cache (R6-proven)
//   + out rows 8*bid..8*bid+7 = beta * v8.

#define NTH 256

struct Params {
  const float* x;     const int* scope;  const float* w_in;
  const int* idx0; const float* w0;  const int* idx1; const float* w1;
  const int* idx2; const float* w2;  const int* idx3; const float* w3;
  const int* idx4; const float* w4;  const int* idx5; const float* w5;
  const int* idx6; const float* w6;  const int* idx7; const float* w7;
  float* h2g;    // ws: [64][64]
  float* v4g;    // ws: [16][64]
  float* betag;  // ws: [2048]
  float* out;  int B;
};

__device__ inline void sinkf4(float4 v) {
  asm volatile("" :: "v"(v.x), "v"(v.y), "v"(v.z), "v"(v.w));
}
__device__ inline float dotp(float4 w, float4 a, float4 b, float acc) {
  acc = fmaf(a.x * b.x, w.x, acc);
  acc = fmaf(a.y * b.y, w.y, acc);
  acc = fmaf(a.z * b.z, w.z, acc);
  acc = fmaf(a.w * b.w, w.w, acc);
  return acc;
}

// ---------------- Node A ----------------------------------------------------
__global__ __launch_bounds__(NTH) void ka_kernel(Params P) {
  const int t = threadIdx.x, bid = blockIdx.x;
  __shared__ float v3[2][64];

  if (bid < 64) {
    // fused level-0 pair + level-1 -> h2g[bid]   (R8-proven body)
    const int o = bid;
    const int ia = P.idx1[2 * o], ib = P.idx1[2 * o + 1];
    {
      const int half = t >> 7, tt = t & 127;    // half 0 -> h1[ia], 1 -> h1[ib]
      const int f = half ? ib : ia;
      const int la = P.idx0[2 * f], lb = P.idx0[2 * f + 1];
      const int oo = tt >> 1, q = tt & 1;       // 2 threads/output, 32 k each
      const float* wr = P.w0   + (size_t)f  * 4096 + oo * 64 + q * 32;
      const float* ar = P.w_in + (size_t)la * 64 + q * 32;
      const float* br = P.w_in + (size_t)lb * 64 + q * 32;
      float acc = 0.f;
      #pragma unroll
      for (int e = 0; e < 8; ++e)
        acc = dotp(*(const float4*)(wr + 4 * e), *(const float4*)(ar + 4 * e),
                   *(const float4*)(br + 4 * e), acc);
      acc += __shfl_xor(acc, 1);
      if (q == 0) v3[half][oo] = acc;
    }
    __syncthreads();
    {
      const int oo = t >> 2, q = t & 3;         // 4 threads/output, 16 k each
      const float* wr = P.w1 + (size_t)o * 4096 + oo * 64 + q * 16;
      float acc = 0.f;
      #pragma unroll
      for (int e = 0; e < 4; ++e)
        acc = dotp(*(const float4*)(wr + 4 * e),
                   *(const float4*)&v3[0][q * 16 + 4 * e],
                   *(const float4*)&v3[1][q * 16 + 4 * e], acc);
      acc += __shfl_xor(acc, 1);
      acc += __shfl_xor(acc, 2);
      if (q == 0) P.h2g[o * 64 + oo] = acc;
    }
  } else if (bid < 192) {
    // beta rows: 16 per block (R6-proven)
    const int r = (bid - 64) * 16 + (t >> 4);
    const int seg = t & 15;
    const float4* xp = (const float4*)(P.x + (size_t)r * 256 + seg * 16);
    float4 u0 = xp[0], u1 = xp[1], u2 = xp[2], u3 = xp[3];
    float pr = ((u0.x * u0.y) * (u0.z * u0.w)) * ((u1.x * u1.y) * (u1.z * u1.w))
             * ((u2.x * u2.y) * (u2.z * u2.w)) * ((u3.x * u3.y) * (u3.z * u3.w));
    pr *= __shfl_xor(pr, 1);
    pr *= __shfl_xor(pr, 2);
    pr *= __shfl_xor(pr, 4);
    pr *= __shfl_xor(pr, 8);
    if (seg == 0) P.betag[r] = pr;
  } else {
    // prefetch slice of concat(w2,w3,w4,w5,w6,w7) = 258048 floats over 64 blks
    const int s = bid - 192;                  // 4032 floats (=1008 float4) each
    const int base = s * 4032;
    for (int i = t * 4; i < 4032; i += NTH * 4) {
      const int fi = base + i;
      const float* p;
      if      (fi < 131072) p = P.w2 + fi;
      else if (fi < 196608) p = P.w3 + (fi - 131072);
      else if (fi < 229376) p = P.w4 + (fi - 196608);
      else if (fi < 245760) p = P.w5 + (fi - 229376);
      else if (fi < 253952) p = P.w6 + (fi - 245760);
      else                  p = P.w7 + (fi - 253952);
      sinkf4(*(const float4*)p);
    }
  }
}

// ---------------- Node B: levels 2-3, 16 blocks -----------------------------
__global__ __launch_bounds__(NTH) void kb_kernel(Params P) {
  const int t = threadIdx.x, g = blockIdx.x;
  __shared__ float h2s[4][64];
  __shared__ float v3[2][64];

  const int a0 = P.idx3[2 * g], a1 = P.idx3[2 * g + 1];
  const int n0 = P.idx2[2 * a0], n1 = P.idx2[2 * a0 + 1];
  const int n2 = P.idx2[2 * a1], n3 = P.idx2[2 * a1 + 1];
  {
    const int r = t >> 6, c = t & 63;
    const int which = (r == 0) ? n0 : (r == 1) ? n1 : (r == 2) ? n2 : n3;
    h2s[r][c] = P.h2g[which * 64 + c];
  }
  __syncthreads();
  {
    const int opq = t >> 7, oo = (t >> 1) & 63, h = t & 1;
    const float* wr = P.w2 + (size_t)(opq ? a1 : a0) * 4096 + oo * 64 + h * 32;
    const float* ar = &h2s[2 * opq + 0][h * 32];
    const float* br = &h2s[2 * opq + 1][h * 32];
    float acc = 0.f;
    #pragma unroll
    for (int e = 0; e < 8; ++e)
      acc = dotp(*(const float4*)(wr + 4 * e), *(const float4*)(ar + 4 * e),
                 *(const float4*)(br + 4 * e), acc);
    acc += __shfl_xor(acc, 1);
    if (h == 0) v3[opq][oo] = acc;
  }
  __syncthreads();
  {
    const int oo = t >> 2, q = t & 3;
    const float* wr = P.w3 + (size_t)g * 4096 + oo * 64 + q * 16;
    float acc = 0.f;
    #pragma unroll
    for (int e = 0; e < 4; ++e)
      acc = dotp(*(const float4*)(wr + 4 * e),
                 *(const float4*)&v3[0][q * 16 + 4 * e],
                 *(const float4*)&v3[1][q * 16 + 4 * e], acc);
    acc += __shfl_xor(acc, 1);
    acc += __shfl_xor(acc, 2);
    if (q == 0) P.v4g[g * 64 + oo] = acc;
  }
}

// ---------------- Node C: redundant fold levels 4-7 + output ----------------
__global__ __launch_bounds__(NTH) void kc_kernel(Params P) {
  const int t = threadIdx.x, bid = blockIdx.x;
  __shared__ float VA[16][64];
  __shared__ float VB[8][64];
  __shared__ float v8[64];
  __shared__ float beta_s[8];

  if (t < 8) beta_s[t] = P.betag[bid * 8 + t];
  #pragma unroll
  for (int rr = 0; rr < 4; ++rr) {
    const int idx = rr * 256 + t;
    VA[rr * 4 + (t >> 6)][idx & 63] = P.v4g[idx];
  }
  __syncthreads();

  const float* wl[4] = {P.w4, P.w5, P.w6, P.w7};
  const int*   il[4] = {P.idx4, P.idx5, P.idx6, P.idx7};
  const int G = t >> 6, lane = t & 63;
  #pragma unroll
  for (int lev = 0; lev < 4; ++lev) {
    const int nops = 8 >> lev;
    for (int op = G; op < nops; op += 4) {
      const int i0 = il[lev][2 * op], i1 = il[lev][2 * op + 1];
      const float* a = (lev & 1) ? VB[i0] : VA[i0];
      const float* b = (lev & 1) ? VB[i1] : VA[i1];
      const float* wp = wl[lev] + (size_t)op * 4096 + lane * 64;
      float acc = 0.f;
      #pragma unroll
      for (int qq = 0; qq < 16; ++qq)
        acc = dotp(*(const float4*)(wp + 4 * qq), *(const float4*)(a + 4 * qq),
                   *(const float4*)(b + 4 * qq), acc);
      float* dst = (lev == 3) ? v8 : ((lev & 1) ? VA[op] : VB[op]);
      dst[lane] = acc;
    }
    __syncthreads();
  }

  {
    const int row = t >> 5, c0 = (t & 31) * 2;
    const float be = beta_s[row];
    float2 v = *(const float2*)&v8[c0];
    *(float2*)(P.out + (size_t)(bid * 8 + row) * 64 + c0) =
        make_float2(be * v.x, be * v.y);
  }
}

extern "C" void kernel_launch(void* const* d_in, const int* in_sizes, int n_in,
                              void* d_out, int out_size, void* d_ws, size_t ws_size,
                              hipStream_t stream) {
  Params P;
  P.x     = (const float*)d_in[0];
  P.scope = (const int*)d_in[1];
  P.w_in  = (const float*)d_in[2];
  P.idx0 = (const int*)d_in[3];  P.w0 = (const float*)d_in[4];
  P.idx1 = (const int*)d_in[5];  P.w1 = (const float*)d_in[6];
  P.idx2 = (const int*)d_in[7];  P.w2 = (const float*)d_in[8];
  P.idx3 = (const int*)d_in[9];  P.w3 = (const float*)d_in[10];
  P.idx4 = (const int*)d_in[11]; P.w4 = (const float*)d_in[12];
  P.idx5 = (const int*)d_in[13]; P.w5 = (const float*)d_in[14];
  P.idx6 = (const int*)d_in[15]; P.w6 = (const float*)d_in[16];
  P.idx7 = (const int*)d_in[17]; P.w7 = (const float*)d_in[18];
  P.B    = in_sizes[0] / 256;              // 2048
  float* ws = (float*)d_ws;
  P.h2g   = ws;                            // [64][64]
  P.v4g   = ws + 64 * 64;                  // [16][64]
  P.betag = ws + 64 * 64 + 16 * 64;        // [2048]
  P.out   = (float*)d_out;

  ka_kernel<<<256, NTH, 0, stream>>>(P);
  kb_kernel<<<16,  NTH, 0, stream>>>(P);
  kc_kernel<<<256, NTH, 0, stream>>>(P);
}